// Round 3
// baseline (287.167 us; speedup 1.0000x reference)
//
#include <hip/hip_runtime.h>
#include <hip/hip_bf16.h>

// Problem constants (match reference)
#define B_  32
#define C_  3
#define HW_ 1024          // N = H*W
#define L_  8             // alphabet
#define P_  16
#define M_  1024
#define NRUN_S  (B_*C_)           // 96
#define NRUN_P  (C_*P_)           // 48
#define NRUN_SP (B_*C_*P_)        // 1536
// Tight dictionary bound for len-2048 LZW over alphabet 8:
// 64 len-2 (64 syms) + 512 len-3 (1024 syms) + 320 len-4 (960 syms) = 896
// entries max; nfree <= 8+896 = 904.
#define TRIE_N  904

// ---------------------------------------------------------------------------
// Kernel 1: quantize  strings[b,c,n] = argmin_l |x[b,c,curve[n]] - levels[c,l]|
// ---------------------------------------------------------------------------
__global__ void quantize_kernel(const float* __restrict__ x,
                                const int* __restrict__ curve,
                                const float* __restrict__ levels,
                                unsigned char* __restrict__ strings) {
    int idx = blockIdx.x * blockDim.x + threadIdx.x;   // [0, 96*1024)
    if (idx >= NRUN_S * HW_) return;
    int n  = idx & (HW_ - 1);
    int bc = idx >> 10;            // b*3 + c
    int c  = bc % C_;
    int pix = curve[n];
    float v = x[bc * HW_ + pix];
    float best = fabsf(v - levels[c * L_ + 0]);
    int bi = 0;
#pragma unroll
    for (int l = 1; l < L_; ++l) {
        float d = fabsf(v - levels[c * L_ + l]);
        if (d < best) { best = d; bi = l; }   // strict < : first-min (matches jnp.argmin)
    }
    strings[idx] = (unsigned char)bi;
}

// ---------------------------------------------------------------------------
// Kernel 2: LZW count per run. One block (64 threads) per run.
// Symbols are nibble-packed into LDS u64s (16 syms each); the serial walker
// (lane 0) keeps a register shift-window of symbols (no LDS read on the
// address-forming path) and issues 3 trie reads per round trip:
//   r0 = trie[cur][s0]   (primary)
//   r1 = trie[s0][s1]    (miss-restart path, input-known)
//   r2 = trie[s1][s2]    (double-miss path, input-known)
// so a miss-run of up to 3 symbols resolves in ONE LDS round trip.
// Stale-read fixups handle writes that land on speculated addresses.
// ---------------------------------------------------------------------------
__global__ void __launch_bounds__(64)
lzw_kernel(const unsigned char* __restrict__ strings,
           const int* __restrict__ pmaps,
           int* __restrict__ cs, int* __restrict__ cp, int* __restrict__ csp) {
    __shared__ short trie[TRIE_N * L_];              // 14464 B
    __shared__ unsigned long long nib[136];          // 1088 B, 16 syms per u64

    const int run = blockIdx.x;
    const int tid = threadIdx.x;

    // parallel trie init to -1 (32-bit stores)
    int* trie32 = (int*)trie;
    for (int i = tid; i < TRIE_N * L_ / 2; i += 64) trie32[i] = -1;

    int len = 0;
    const unsigned char* sp = nullptr;
    const int* pp = nullptr;
    int pbase = 0;   // u64 index where pmap nibbles start

    if (run < NRUN_S) {
        sp = strings + run * HW_;  len = HW_;
    } else if (run < NRUN_S + NRUN_P) {
        int idx = run - NRUN_S;                 // c*16 + p
        pp = pmaps + idx * M_;  len = M_;  pbase = 0;
    } else {
        int idx = run - (NRUN_S + NRUN_P);      // (b*3+c)*16 + p
        int bc = idx >> 4;
        int c  = bc % C_;
        int p  = idx & 15;
        sp = strings + bc * HW_;
        pp = pmaps + (c * P_ + p) * M_;
        len = HW_ + M_;  pbase = HW_ / 16;      // 64
    }

    if (sp) {  // 1024 string bytes -> 64 u64s; thread i packs bytes [16i,16i+16)
        const int4* s4 = (const int4*)sp;
        int4 v = s4[tid];
        unsigned long long r = 0;
        unsigned u;
        u = (unsigned)v.x; r |= (unsigned long long)((u & 7u) | ((u >> 4) & 0x70u) | ((u >> 8) & 0x700u) | ((u >> 12) & 0x7000u));
        u = (unsigned)v.y; r |= (unsigned long long)((u & 7u) | ((u >> 4) & 0x70u) | ((u >> 8) & 0x700u) | ((u >> 12) & 0x7000u)) << 16;
        u = (unsigned)v.z; r |= (unsigned long long)((u & 7u) | ((u >> 4) & 0x70u) | ((u >> 8) & 0x700u) | ((u >> 12) & 0x7000u)) << 32;
        u = (unsigned)v.w; r |= (unsigned long long)((u & 7u) | ((u >> 4) & 0x70u) | ((u >> 8) & 0x700u) | ((u >> 12) & 0x7000u)) << 48;
        nib[tid] = r;
    }
    if (pp) {  // 1024 pmap ints -> 64 u64s; thread i packs ints [16i,16i+16)
        const int4* p4 = (const int4*)pp;
        unsigned long long r = 0;
#pragma unroll
        for (int k = 0; k < 4; ++k) {
            int4 q = p4[tid * 4 + k];
            unsigned part = (unsigned)(q.x & 7) | ((unsigned)(q.y & 7) << 4) |
                            ((unsigned)(q.z & 7) << 8) | ((unsigned)(q.w & 7) << 12);
            r |= (unsigned long long)part << (16 * k);
        }
        nib[pbase + tid] = r;
    }
    // zero 8 pad u64s past the data (refill prefetch may read them)
    {
        int nu64 = len / 16;
        if (tid < 8) nib[nu64 + tid] = 0;
    }
    __syncthreads();

    if (tid == 0) {
        // register symbol window: w0 holds nibbles 0..15, w1 nibbles 16..31,
        // low-aligned; nibbles >= nv are zero. pend = prefetched next 16.
        unsigned long long w0 = nib[0], w1 = nib[1], pend = nib[2];
        int pos = 3;
        int nv = 32;

        int cur = (int)(w0 & 7);
        w0 = (w0 >> 4) | (w1 << 60); w1 >>= 4; nv--;

        int remaining = len - 1;
        int nfree = L_, cnt = 0;
        int s0 = (int)(w0 & 7), s1 = (int)((w0 >> 4) & 7), s2 = (int)((w0 >> 8) & 7);

        while (remaining >= 3) {
            int a0 = (cur << 3) | s0;
            int a1 = (s0  << 3) | s1;
            int a2 = (s1  << 3) | s2;
            int r0 = trie[a0];
            int r1 = trie[a1];
            int r2 = trie[a2];
            int adv;
            if (r0 >= 0) {
                cur = r0; adv = 1;
            } else {
                trie[a0] = (short)nfree; int v0 = nfree++; cnt++;
                int val1 = (a1 == a0) ? v0 : r1;            // stale fixup
                if (val1 >= 0) {
                    cur = val1; adv = 2;
                } else {
                    trie[a1] = (short)nfree; int v1 = nfree++; cnt++;
                    int val2 = (a2 == a1) ? v1 : ((a2 == a0) ? v0 : r2);  // latest write first
                    if (val2 >= 0) {
                        cur = val2; adv = 3;
                    } else {
                        trie[a2] = (short)nfree; nfree++; cnt++;
                        cur = s2; adv = 3;
                    }
                }
            }
            remaining -= adv;
            int sh = adv * 4;
            w0 = (w0 >> sh) | (w1 << (64 - sh)); w1 >>= sh; nv -= adv;
            if (nv <= 16) {          // merge prefetched u64 at nibble position nv
                int msh = nv * 4;
                if (nv == 0)        { w0 = pend; }
                else if (nv < 16)   { w0 |= pend << msh; w1 |= pend >> (64 - msh); }
                else                { w1 = pend; }
                nv += 16;
                pend = nib[pos]; pos++;
            }
            s0 = (int)(w0 & 7); s1 = (int)((w0 >> 4) & 7); s2 = (int)((w0 >> 8) & 7);
        }
        // tail: 0..2 symbols left, one at a time
        while (remaining > 0) {
            int a0 = (cur << 3) | s0;
            int r0 = trie[a0];
            if (r0 >= 0) cur = r0;
            else { trie[a0] = (short)nfree; nfree++; cnt++; cur = s0; }
            w0 = (w0 >> 4) | (w1 << 60); w1 >>= 4;
            s0 = (int)(w0 & 7);
            remaining--;
        }

        int result = cnt + 1;
        if (run < NRUN_S)                cs[run] = result;
        else if (run < NRUN_S + NRUN_P)  cp[run - NRUN_S] = result;
        else                             csp[run - (NRUN_S + NRUN_P)] = result;
    }
}

// ---------------------------------------------------------------------------
// Kernel 3: NCD epilogue
// ---------------------------------------------------------------------------
__global__ void ncd_kernel(const int* __restrict__ cs,
                           const int* __restrict__ cp,
                           const int* __restrict__ csp,
                           float* __restrict__ out) {
    int idx = blockIdx.x * blockDim.x + threadIdx.x;
    if (idx >= NRUN_SP) return;
    int p  = idx & 15;
    int bc = idx >> 4;         // b*3 + c
    int c  = bc % C_;
    float a  = (float)cs[bc];
    float b  = (float)cp[c * P_ + p];
    float ab = (float)csp[idx];
    out[idx] = (ab - fminf(a, b)) / fmaxf(a, b);
}

// ---------------------------------------------------------------------------
extern "C" void kernel_launch(void* const* d_in, const int* in_sizes, int n_in,
                              void* d_out, int out_size, void* d_ws, size_t ws_size,
                              hipStream_t stream) {
    const float* x      = (const float*)d_in[0];   // [B,C,H,W] f32
    const int*   curve  = (const int*)d_in[1];     // [N] int32
    const float* levels = (const float*)d_in[2];   // [C,L] f32
    const int*   pmaps  = (const int*)d_in[3];     // [C,P,M] int32
    // d_in[4] = i (unused)

    float* out = (float*)d_out;

    unsigned char* strings = (unsigned char*)d_ws;            // 96*1024 bytes
    int* cs  = (int*)((char*)d_ws + NRUN_S * HW_);            // 96
    int* cp  = cs + NRUN_S;                                   // 48
    int* csp = cp + NRUN_P;                                   // 1536

    quantize_kernel<<<(NRUN_S * HW_ + 255) / 256, 256, 0, stream>>>(x, curve, levels, strings);
    lzw_kernel<<<NRUN_S + NRUN_P + NRUN_SP, 64, 0, stream>>>(strings, pmaps, cs, cp, csp);
    ncd_kernel<<<(NRUN_SP + 255) / 256, 256, 0, stream>>>(cs, cp, csp, out);
}

// Round 4
// 229.039 us; speedup vs baseline: 1.2538x; 1.2538x over previous
//
#include <hip/hip_runtime.h>
#include <hip/hip_bf16.h>

// Problem constants (match reference)
#define B_  32
#define C_  3
#define HW_ 1024          // N = H*W
#define L_  8             // alphabet
#define P_  16
#define M_  1024
#define NRUN_S  (B_*C_)           // 96
#define NRUN_P  (C_*P_)           // 48
#define NRUN_SP (B_*C_*P_)        // 1536
// Tight dictionary bound for len-2048 LZW over alphabet 8:
// 64 len-2 (64 syms) + 512 len-3 (1024 syms) + 320 len-4 (960 syms) = 896
// entries max; nfree <= 8+896 = 904.
#define TRIE_N  904

// ---------------------------------------------------------------------------
// Kernel 1: quantize  strings[b,c,n] = argmin_l |x[b,c,curve[n]] - levels[c,l]|
// ---------------------------------------------------------------------------
__global__ void quantize_kernel(const float* __restrict__ x,
                                const int* __restrict__ curve,
                                const float* __restrict__ levels,
                                unsigned char* __restrict__ strings) {
    int idx = blockIdx.x * blockDim.x + threadIdx.x;   // [0, 96*1024)
    if (idx >= NRUN_S * HW_) return;
    int n  = idx & (HW_ - 1);
    int bc = idx >> 10;            // b*3 + c
    int c  = bc % C_;
    int pix = curve[n];
    float v = x[bc * HW_ + pix];
    float best = fabsf(v - levels[c * L_ + 0]);
    int bi = 0;
#pragma unroll
    for (int l = 1; l < L_; ++l) {
        float d = fabsf(v - levels[c * L_ + l]);
        if (d < best) { best = d; bi = l; }   // strict < : first-min (matches jnp.argmin)
    }
    strings[idx] = (unsigned char)bi;
}

// ---------------------------------------------------------------------------
// Kernel 2: LZW count per run. One block (64 threads) per run.
// Minimal-latency serial walker (lane 0):
//   - trie sentinel init: empty entry trie[node][c] = c, so `cur = trie[a]`
//     unconditionally (real codes are >= 8; r < 8  <=>  miss, and r is then
//     exactly the restart symbol). Hit/miss bookkeeping is OFF the chain.
//   - symbols nibble-packed in LDS u64s; 16 steps fully unrolled per u64 with
//     compile-time shifts; next u64 prefetched one block ahead.
//   - chain per step: v_lshl_add (addr) + ds_read_u16  (~125 cy).
// ---------------------------------------------------------------------------
__global__ void __launch_bounds__(64)
lzw_kernel(const unsigned char* __restrict__ strings,
           const int* __restrict__ pmaps,
           int* __restrict__ cs, int* __restrict__ cp, int* __restrict__ csp) {
    __shared__ unsigned short trie[TRIE_N * L_];     // 14464 B
    __shared__ unsigned long long nib[136];          // 1088 B, 16 syms per u64

    const int run = blockIdx.x;
    const int tid = threadIdx.x;

    // parallel sentinel init: entry e holds (e & 7). 32-bit store covers
    // entries 2i (even c0) and 2i+1 (c0+1).
    unsigned int* trie32 = (unsigned int*)trie;
    for (int i = tid; i < TRIE_N * L_ / 2; i += 64) {
        unsigned c0 = (i & 3) << 1;
        trie32[i] = c0 | ((c0 + 1) << 16);
    }

    int len = 0;
    const unsigned char* sp = nullptr;
    const int* pp = nullptr;
    int pbase = 0;   // u64 index where pmap nibbles start

    if (run < NRUN_S) {
        sp = strings + run * HW_;  len = HW_;
    } else if (run < NRUN_S + NRUN_P) {
        int idx = run - NRUN_S;                 // c*16 + p
        pp = pmaps + idx * M_;  len = M_;  pbase = 0;
    } else {
        int idx = run - (NRUN_S + NRUN_P);      // (b*3+c)*16 + p
        int bc = idx >> 4;
        int c  = bc % C_;
        int p  = idx & 15;
        sp = strings + bc * HW_;
        pp = pmaps + (c * P_ + p) * M_;
        len = HW_ + M_;  pbase = HW_ / 16;      // 64
    }

    if (sp) {  // 1024 string bytes -> 64 u64s; thread i packs bytes [16i,16i+16)
        const int4* s4 = (const int4*)sp;
        int4 v = s4[tid];
        unsigned long long r = 0;
        unsigned u;
        u = (unsigned)v.x; r |= (unsigned long long)((u & 7u) | ((u >> 4) & 0x70u) | ((u >> 8) & 0x700u) | ((u >> 12) & 0x7000u));
        u = (unsigned)v.y; r |= (unsigned long long)((u & 7u) | ((u >> 4) & 0x70u) | ((u >> 8) & 0x700u) | ((u >> 12) & 0x7000u)) << 16;
        u = (unsigned)v.z; r |= (unsigned long long)((u & 7u) | ((u >> 4) & 0x70u) | ((u >> 8) & 0x700u) | ((u >> 12) & 0x7000u)) << 32;
        u = (unsigned)v.w; r |= (unsigned long long)((u & 7u) | ((u >> 4) & 0x70u) | ((u >> 8) & 0x700u) | ((u >> 12) & 0x7000u)) << 48;
        nib[tid] = r;
    }
    if (pp) {  // 1024 pmap ints -> 64 u64s; thread i packs ints [16i,16i+16)
        const int4* p4 = (const int4*)pp;
        unsigned long long r = 0;
#pragma unroll
        for (int k = 0; k < 4; ++k) {
            int4 q = p4[tid * 4 + k];
            unsigned part = (unsigned)(q.x & 7) | ((unsigned)(q.y & 7) << 4) |
                            ((unsigned)(q.z & 7) << 8) | ((unsigned)(q.w & 7) << 12);
            r |= (unsigned long long)part << (16 * k);
        }
        nib[pbase + tid] = r;
    }
    // zero pad u64s past the data (prefetch reads one past the end)
    {
        int nu64 = len >> 4;
        if (tid < 8) nib[nu64 + tid] = 0;
    }
    __syncthreads();

    if (tid == 0) {
        const char* tb = (const char*)trie;
        char* tw = (char*)trie;
        int nfree = L_, cnt = 0;

        unsigned long long w = nib[0];
        int cur = (int)(w & 7);
        w >>= 4;
        const int nu64 = len >> 4;
        unsigned long long wnext = nib[1];

        // STEP: chain = (cur<<4)+s2 -> ds_read_u16. Everything else trails.
#define LZW_STEP(S2)                                                      \
        {                                                                 \
            int a2 = (cur << 4) + (S2);                                   \
            int r  = *(const unsigned short*)(tb + a2);                   \
            int m  = (r < 8) ? 1 : 0;                                     \
            *(unsigned short*)(tw + a2) =                                 \
                (unsigned short)(m ? nfree : r);                          \
            nfree += m; cnt += m; cur = r;                                \
        }

#pragma unroll
        for (int j = 0; j < 15; ++j) {
            int s2 = ((int)((w >> (4 * j)) & 7)) << 1;
            LZW_STEP(s2);
        }
        for (int k = 1; k < nu64; ++k) {
            unsigned long long wk = wnext;
            wnext = nib[k + 1];
#pragma unroll
            for (int j = 0; j < 16; ++j) {
                int s2 = ((int)((wk >> (4 * j)) & 7)) << 1;
                LZW_STEP(s2);
            }
        }
#undef LZW_STEP

        int result = cnt + 1;
        if (run < NRUN_S)                cs[run] = result;
        else if (run < NRUN_S + NRUN_P)  cp[run - NRUN_S] = result;
        else                             csp[run - (NRUN_S + NRUN_P)] = result;
    }
}

// ---------------------------------------------------------------------------
// Kernel 3: NCD epilogue
// ---------------------------------------------------------------------------
__global__ void ncd_kernel(const int* __restrict__ cs,
                           const int* __restrict__ cp,
                           const int* __restrict__ csp,
                           float* __restrict__ out) {
    int idx = blockIdx.x * blockDim.x + threadIdx.x;
    if (idx >= NRUN_SP) return;
    int p  = idx & 15;
    int bc = idx >> 4;         // b*3 + c
    int c  = bc % C_;
    float a  = (float)cs[bc];
    float b  = (float)cp[c * P_ + p];
    float ab = (float)csp[idx];
    out[idx] = (ab - fminf(a, b)) / fmaxf(a, b);
}

// ---------------------------------------------------------------------------
extern "C" void kernel_launch(void* const* d_in, const int* in_sizes, int n_in,
                              void* d_out, int out_size, void* d_ws, size_t ws_size,
                              hipStream_t stream) {
    const float* x      = (const float*)d_in[0];   // [B,C,H,W] f32
    const int*   curve  = (const int*)d_in[1];     // [N] int32
    const float* levels = (const float*)d_in[2];   // [C,L] f32
    const int*   pmaps  = (const int*)d_in[3];     // [C,P,M] int32
    // d_in[4] = i (unused)

    float* out = (float*)d_out;

    unsigned char* strings = (unsigned char*)d_ws;            // 96*1024 bytes
    int* cs  = (int*)((char*)d_ws + NRUN_S * HW_);            // 96
    int* cp  = cs + NRUN_S;                                   // 48
    int* csp = cp + NRUN_P;                                   // 1536

    quantize_kernel<<<(NRUN_S * HW_ + 255) / 256, 256, 0, stream>>>(x, curve, levels, strings);
    lzw_kernel<<<NRUN_S + NRUN_P + NRUN_SP, 64, 0, stream>>>(strings, pmaps, cs, cp, csp);
    ncd_kernel<<<(NRUN_SP + 255) / 256, 256, 0, stream>>>(cs, cp, csp, out);
}

// Round 5
// 128.276 us; speedup vs baseline: 2.2387x; 1.7855x over previous
//
#include <hip/hip_runtime.h>
#include <hip/hip_bf16.h>

// Problem constants (match reference)
#define B_  32
#define C_  3
#define HW_ 1024          // N = H*W
#define L_  8             // alphabet
#define P_  16
#define M_  1024
#define NRUN_S  (B_*C_)           // 96
#define NRUN_P  (C_*P_)           // 48
#define NRUN_SP (B_*C_*P_)        // 1536
// Tight dictionary bound for len-2048 LZW over alphabet 8:
// 64 len-2 + 512 len-3 + 320 len-4 = 896 entries max; nfree <= 8+896 = 904.
#define TRIE_N  904
#define DUMMY_OFF (TRIE_N * L_ * 2)   // byte offset of dummy (scratch) entry

// ---------------------------------------------------------------------------
// Kernel 1: quantize  strings[b,c,n] = argmin_l |x[b,c,curve[n]] - levels[c,l]|
// ---------------------------------------------------------------------------
__global__ void quantize_kernel(const float* __restrict__ x,
                                const int* __restrict__ curve,
                                const float* __restrict__ levels,
                                unsigned char* __restrict__ strings) {
    int idx = blockIdx.x * blockDim.x + threadIdx.x;   // [0, 96*1024)
    if (idx >= NRUN_S * HW_) return;
    int n  = idx & (HW_ - 1);
    int bc = idx >> 10;            // b*3 + c
    int c  = bc % C_;
    int pix = curve[n];
    float v = x[bc * HW_ + pix];
    float best = fabsf(v - levels[c * L_ + 0]);
    int bi = 0;
#pragma unroll
    for (int l = 1; l < L_; ++l) {
        float d = fabsf(v - levels[c * L_ + l]);
        if (d < best) { best = d; bi = l; }   // strict < : first-min (matches jnp.argmin)
    }
    strings[idx] = (unsigned char)bi;
}

// ---------------------------------------------------------------------------
// Kernel 2: LZW count per run. One block (64 threads) per run.
// Minimal-latency serial walker (lane 0):
//   - sentinel init: empty entry trie[node][c] = c, so r<8 <=> miss and r is
//     then the restart symbol -> `cur = r` unconditionally.
//   - DEFERRED WRITE: the dictionary write from step t is issued AFTER the
//     read of step t+1 (reads issue first in program order). The only hazard
//     is a_{t+1}==a_t (e.g. "aaa"); fixed by r = (a==ap)?vp:r_raw, with the
//     compare precomputed while the read is in flight. Distance>=2 is safe
//     (DS pipe processes same-wave ops in program order).
//   - on hit the pending write targets a DUMMY slot (branchless).
//   - chain per step: waitcnt -> cndmask(fixup) -> lshl_add -> ds_read.
// ---------------------------------------------------------------------------
__global__ void __launch_bounds__(64)
lzw_kernel(const unsigned char* __restrict__ strings,
           const int* __restrict__ pmaps,
           int* __restrict__ cs, int* __restrict__ cp, int* __restrict__ csp) {
    __shared__ unsigned short trie[TRIE_N * L_ + 8]; // +8: dummy slot (16 B)
    __shared__ unsigned long long nib[136];          // 1088 B, 16 syms per u64

    const int run = blockIdx.x;
    const int tid = threadIdx.x;

    // parallel sentinel init: entry e holds (e & 7). 32-bit store covers
    // entries 2i (even c0) and 2i+1 (c0+1).
    unsigned int* trie32 = (unsigned int*)trie;
    for (int i = tid; i < TRIE_N * L_ / 2; i += 64) {
        unsigned c0 = (i & 3) << 1;
        trie32[i] = c0 | ((c0 + 1) << 16);
    }

    int len = 0;
    const unsigned char* sp = nullptr;
    const int* pp = nullptr;
    int pbase = 0;   // u64 index where pmap nibbles start

    if (run < NRUN_S) {
        sp = strings + run * HW_;  len = HW_;
    } else if (run < NRUN_S + NRUN_P) {
        int idx = run - NRUN_S;                 // c*16 + p
        pp = pmaps + idx * M_;  len = M_;  pbase = 0;
    } else {
        int idx = run - (NRUN_S + NRUN_P);      // (b*3+c)*16 + p
        int bc = idx >> 4;
        int c  = bc % C_;
        int p  = idx & 15;
        sp = strings + bc * HW_;
        pp = pmaps + (c * P_ + p) * M_;
        len = HW_ + M_;  pbase = HW_ / 16;      // 64
    }

    if (sp) {  // 1024 string bytes -> 64 u64s; thread i packs bytes [16i,16i+16)
        const int4* s4 = (const int4*)sp;
        int4 v = s4[tid];
        unsigned long long r = 0;
        unsigned u;
        u = (unsigned)v.x; r |= (unsigned long long)((u & 7u) | ((u >> 4) & 0x70u) | ((u >> 8) & 0x700u) | ((u >> 12) & 0x7000u));
        u = (unsigned)v.y; r |= (unsigned long long)((u & 7u) | ((u >> 4) & 0x70u) | ((u >> 8) & 0x700u) | ((u >> 12) & 0x7000u)) << 16;
        u = (unsigned)v.z; r |= (unsigned long long)((u & 7u) | ((u >> 4) & 0x70u) | ((u >> 8) & 0x700u) | ((u >> 12) & 0x7000u)) << 32;
        u = (unsigned)v.w; r |= (unsigned long long)((u & 7u) | ((u >> 4) & 0x70u) | ((u >> 8) & 0x700u) | ((u >> 12) & 0x7000u)) << 48;
        nib[tid] = r;
    }
    if (pp) {  // 1024 pmap ints -> 64 u64s; thread i packs ints [16i,16i+16)
        const int4* p4 = (const int4*)pp;
        unsigned long long r = 0;
#pragma unroll
        for (int k = 0; k < 4; ++k) {
            int4 q = p4[tid * 4 + k];
            unsigned part = (unsigned)(q.x & 7) | ((unsigned)(q.y & 7) << 4) |
                            ((unsigned)(q.z & 7) << 8) | ((unsigned)(q.w & 7) << 12);
            r |= (unsigned long long)part << (16 * k);
        }
        nib[pbase + tid] = r;
    }
    // zero pad u64s past the data (prefetch reads one past the end)
    {
        int nu64 = len >> 4;
        if (tid < 8) nib[nu64 + tid] = 0;
    }
    __syncthreads();

    if (tid == 0) {
        const char* tb = (const char*)trie;
        char* tw = (char*)trie;
        int nfree = L_, cnt = 0;
        int ap = DUMMY_OFF, vp = 8;      // pending write (byte addr, value)

        unsigned long long w = nib[0];
        int cur = (int)(w & 7);
        w >>= 4;
        const int nu64 = len >> 4;
        unsigned long long wnext = nib[1];

        // chain: cndmask(fixup) -> lshl_add -> ds_read. Write trails (issued
        // after the read; distance-1 hazard handled by the fixup).
#define LZW_STEP(S2)                                                      \
        {                                                                 \
            int a = (cur << 4) + (S2);                                    \
            int r_raw = *(const unsigned short*)(tb + a);                 \
            *(unsigned short*)(tw + ap) = (unsigned short)vp;             \
            int r = (a == ap) ? vp : r_raw;                               \
            int m = (r < 8) ? 1 : 0;                                      \
            ap = m ? a : DUMMY_OFF;                                       \
            vp = nfree;                                                   \
            nfree += m; cnt += m;                                         \
            cur = r;                                                      \
        }

#pragma unroll
        for (int j = 0; j < 15; ++j) {
            int s2 = ((int)((w >> (4 * j)) & 7)) << 1;
            LZW_STEP(s2);
        }
        for (int k = 1; k < nu64; ++k) {
            unsigned long long wk = wnext;
            wnext = nib[k + 1];
#pragma unroll
            for (int j = 0; j < 16; ++j) {
                int s2 = ((int)((wk >> (4 * j)) & 7)) << 1;
                LZW_STEP(s2);
            }
        }
#undef LZW_STEP

        int result = cnt + 1;
        if (run < NRUN_S)                cs[run] = result;
        else if (run < NRUN_S + NRUN_P)  cp[run - NRUN_S] = result;
        else                             csp[run - (NRUN_S + NRUN_P)] = result;
    }
}

// ---------------------------------------------------------------------------
// Kernel 3: NCD epilogue
// ---------------------------------------------------------------------------
__global__ void ncd_kernel(const int* __restrict__ cs,
                           const int* __restrict__ cp,
                           const int* __restrict__ csp,
                           float* __restrict__ out) {
    int idx = blockIdx.x * blockDim.x + threadIdx.x;
    if (idx >= NRUN_SP) return;
    int p  = idx & 15;
    int bc = idx >> 4;         // b*3 + c
    int c  = bc % C_;
    float a  = (float)cs[bc];
    float b  = (float)cp[c * P_ + p];
    float ab = (float)csp[idx];
    out[idx] = (ab - fminf(a, b)) / fmaxf(a, b);
}

// ---------------------------------------------------------------------------
extern "C" void kernel_launch(void* const* d_in, const int* in_sizes, int n_in,
                              void* d_out, int out_size, void* d_ws, size_t ws_size,
                              hipStream_t stream) {
    const float* x      = (const float*)d_in[0];   // [B,C,H,W] f32
    const int*   curve  = (const int*)d_in[1];     // [N] int32
    const float* levels = (const float*)d_in[2];   // [C,L] f32
    const int*   pmaps  = (const int*)d_in[3];     // [C,P,M] int32
    // d_in[4] = i (unused)

    float* out = (float*)d_out;

    unsigned char* strings = (unsigned char*)d_ws;            // 96*1024 bytes
    int* cs  = (int*)((char*)d_ws + NRUN_S * HW_);            // 96
    int* cp  = cs + NRUN_S;                                   // 48
    int* csp = cp + NRUN_P;                                   // 1536

    quantize_kernel<<<(NRUN_S * HW_ + 255) / 256, 256, 0, stream>>>(x, curve, levels, strings);
    lzw_kernel<<<NRUN_S + NRUN_P + NRUN_SP, 64, 0, stream>>>(strings, pmaps, cs, cp, csp);
    ncd_kernel<<<(NRUN_SP + 255) / 256, 256, 0, stream>>>(cs, cp, csp, out);
}